// Round 1
// 760.078 us; speedup vs baseline: 1.1483x; 1.1483x over previous
//
#include <hip/hip_runtime.h>
#include <hip/hip_fp16.h>
#include <math.h>

// dst-CSR built with ZERO N-wide passes (unchanged):
//   bucket_hist_k / bucket_scan_k / binsort_k / fill2_k.
// gemm_k: NO W staging (W is L1-resident, 32 KB), 64-row x tile (34 KB LDS)
//         -> 4 blocks/CU (was 1 block/CU at 100 KB LDS).
// prop_k: 8-lanes-per-row float4 gathers -> 8 edges per load instruction,
//         32 edges in flight per wave; shfl-distributed cols (no readlanes).

#define BSH 8   // 256 dsts per bucket

// ---------------- small utils ----------------

__global__ void zero_i32(int* __restrict__ p, int n) {
    int i = blockIdx.x * blockDim.x + threadIdx.x;
    if (i < n) p[i] = 0;
}

// zero dummy row N (32 half2) of the three gather buffers
__global__ void zero_dummy(__half2* __restrict__ b0, __half2* __restrict__ b1,
                           __half2* __restrict__ b2, int N) {
    int t = threadIdx.x;
    if (t >= 96) return;
    __half2* b = (t < 32) ? b0 : (t < 64) ? b1 : b2;
    b[(size_t)N * 32 + (t & 31)] = __floats2half2_rn(0.f, 0.f);
}

// ---------------- bucket histogram (LDS-aggregated) ----------------

__global__ void __launch_bounds__(256) bucket_hist_k(const int* __restrict__ dst, int E,
                                                     int* __restrict__ bktcnt) {
    __shared__ int hist[400];
    int t = threadIdx.x;
    for (int i = t; i < 400; i += 256) hist[i] = 0;
    __syncthreads();
    int e0 = blockIdx.x * 4096 + t;
#pragma unroll
    for (int i = 0; i < 16; ++i) {
        int e = e0 + i * 256;
        if (e < E) atomicAdd(&hist[dst[e] >> BSH], 1);
    }
    __syncthreads();
    for (int b = t; b < 400; b += 256) {
        int c = hist[b];
        if (c > 0) atomicAdd(&bktcnt[b], c);
    }
}

// ---------------- 1-block scan of bucket totals -> bases + padded cursors ----------------

__global__ void bucket_scan_k(const int* __restrict__ bktcnt, int nb, int E,
                              int* __restrict__ bktbase, int* __restrict__ bktcur) {
    __shared__ int s[256];
    int t = threadIdx.x;
    int C = (nb + 255) / 256;            // <= 8
    int b0 = t * C;
    int loc[8]; int sum = 0;
    for (int i = 0; i < C; ++i) {
        int v = (b0 + i < nb) ? bktcnt[b0 + i] : 0;
        loc[i] = sum; sum += v;
    }
    s[t] = sum; __syncthreads();
    for (int off = 1; off < 256; off <<= 1) {
        int v = (t >= off) ? s[t - off] : 0;
        __syncthreads();
        s[t] += v;
        __syncthreads();
    }
    int excl = s[t] - sum;
    for (int i = 0; i < C; ++i)
        if (b0 + i < nb) {
            int e0 = excl + loc[i];
            bktbase[b0 + i] = e0;
            bktcur[(b0 + i) * 16] = e0;  // 64B-padded cursor
        }
    if (t == 0) bktbase[nb] = E;
}

// ---------------- bin edges by bucket (dst>>8), contiguous runs ----------------

__global__ void __launch_bounds__(256) binsort_k(const int* __restrict__ src,
                                                 const int* __restrict__ dst, int E,
                                                 int* __restrict__ bktcur,  // padded x16
                                                 unsigned* __restrict__ binned) {
    __shared__ int hist[400], gbase[400], lcur[400];
    int t = threadIdx.x;
    for (int i = t; i < 400; i += 256) { hist[i] = 0; lcur[i] = 0; }
    __syncthreads();

    int e0 = blockIdx.x * 4096 + t;
    unsigned rec[16]; int bk[16];
#pragma unroll
    for (int i = 0; i < 16; ++i) {
        int e = e0 + i * 256;
        if (e < E) {
            int s = src[e], d = dst[e];
            bk[i]  = d >> BSH;
            rec[i] = ((unsigned)s << BSH) | (unsigned)(d & 255);
            atomicAdd(&hist[bk[i]], 1);
        } else bk[i] = -1;
    }
    __syncthreads();
    for (int b = t; b < 400; b += 256) {
        int c = hist[b];
        if (c > 0) gbase[b] = atomicAdd(&bktcur[b * 16], c);
    }
    __syncthreads();
#pragma unroll
    for (int i = 0; i < 16; ++i) {
        if (bk[i] >= 0) {
            int loc = atomicAdd(&lcur[bk[i]], 1);
            binned[gbase[bk[i]] + loc] = rec[i];
        }
    }
}

// ---------------- per-bucket: degrees + rowptr + dinv + col scatter ----------------

__global__ void __launch_bounds__(256) fill2_k(const unsigned* __restrict__ binned,
                                               const int* __restrict__ bktbase,
                                               int N, int E, int NB,
                                               int* __restrict__ rowptr,
                                               float* __restrict__ dinv,
                                               int* __restrict__ col) {
    __shared__ int cnt[256], excl[256], lcur[256];
    int b = blockIdx.x, t = threadIdx.x;
    int beg = bktbase[b], end = bktbase[b + 1];
    cnt[t] = 0;
    __syncthreads();
    for (int i = beg + t; i < end; i += 256)
        atomicAdd(&cnt[binned[i] & 255u], 1);
    __syncthreads();
    int v = cnt[t];
    excl[t] = v;
    __syncthreads();
    for (int off = 1; off < 256; off <<= 1) {
        int u = (t >= off) ? excl[t - off] : 0;
        __syncthreads();
        excl[t] += u;
        __syncthreads();
    }
    int ex = excl[t] - v;                // exclusive prefix within bucket
    lcur[t] = ex;
    int d = (b << BSH) + t;
    if (d < N) {
        rowptr[d] = beg + ex;            // coalesced
        dinv[d] = rsqrtf((float)(v + 1));  // +1 self-loop
    }
    if (b == NB - 1 && t == 0) rowptr[N] = E;
    __syncthreads();
    for (int i = beg + t; i < end; i += 256) {
        unsigned r = binned[i];
        int loc = atomicAdd(&lcur[r & 255u], 1);
        col[beg + loc] = (int)(r >> BSH);   // scatter inside this bucket's segment
    }
}

// ---------------- g0 = x @ W : 64-row tile, W read from global (L1-resident) ----------------
// Emits TWO fp16 buffers: g0h = dinv[n]*g0[n] (gather state, +dummy row) and
// g0f = g0[n] (teleport term).

__global__ void __launch_bounds__(256) gemm_k(const float* __restrict__ x,
                                              const float* __restrict__ W,
                                              const float* __restrict__ dinv,
                                              __half2* __restrict__ g0f,
                                              __half2* __restrict__ g0h, int N) {
    __shared__ float xs[64 * 133];        // ~34 KB -> 4 blocks/CU
    int t = threadIdx.x;
    int n0 = blockIdx.x * 64;
    // stage 64 rows x 128 cols: 2048 float4 / 256 thr = 8 each, coalesced
    for (int f = t; f < 64 * 32; f += 256) {
        int r = f >> 5, c4 = f & 31;
        int n = n0 + r;
        float4 v = (n < N) ? ((const float4*)x)[(size_t)n * 32 + c4]
                           : make_float4(0.f, 0.f, 0.f, 0.f);
        float* dp = &xs[r * 133 + c4 * 4];
        dp[0] = v.x; dp[1] = v.y; dp[2] = v.z; dp[3] = v.w;
    }
    __syncthreads();
    int tr = t & 15, tc = t >> 4;         // tr: 16 j-groups of 4, tc: 16 row-groups of 4
    int j0 = tr * 4, r0 = tc * 4;
    const float4* W4 = (const float4*)W;  // W[k*64 + j], 32 KB total -> L1-resident
    float acc[4][4] = {};
#pragma unroll 8
    for (int k = 0; k < 128; ++k) {
        float4 wv = W4[k * 16 + tr];      // 256 B/k, broadcast across tc, L1 hit
#pragma unroll
        for (int i = 0; i < 4; ++i) {
            float xv = xs[(r0 + i) * 133 + k];
            acc[i][0] += xv * wv.x; acc[i][1] += xv * wv.y;
            acc[i][2] += xv * wv.z; acc[i][3] += xv * wv.w;
        }
    }
    int h0 = j0 >> 1;
#pragma unroll
    for (int i = 0; i < 4; ++i) {
        int n = n0 + r0 + i;
        if (n < N) {
            float dn = dinv[n];
            __half2* gf = &g0f[(size_t)n * 32 + h0];
            gf[0] = __floats2half2_rn(acc[i][0], acc[i][1]);
            gf[1] = __floats2half2_rn(acc[i][2], acc[i][3]);
            __half2* gp = &g0h[(size_t)n * 32 + h0];
            gp[0] = __floats2half2_rn(acc[i][0] * dn, acc[i][1] * dn);
            gp[1] = __floats2half2_rn(acc[i][2] * dn, acc[i][3] * dn);
        }
    }
}

// ---------------- propagation: 8 lanes per row, float4 gathers ----------------
// Wave = 1 dst row. lane = sub*8 + q: sub in [0,8) = edge slot, q in [0,8) = 16B
// segment of the 128 B fp16 row. One gather instruction covers 8 edges
// (64 lanes x 16 B = 8 full rows); unroll 4 -> 32 edges in flight per wave.

__global__ void __launch_bounds__(256) prop_k(const __half2* __restrict__ gin,
                                              const __half2* __restrict__ g0f,
                                              __half2* __restrict__ gout,
                                              float* __restrict__ outf,
                                              const int* __restrict__ rowptr,
                                              const int* __restrict__ cols,
                                              const float* __restrict__ dinv,
                                              const float* __restrict__ bias,
                                              int N, int final_step) {
    int gw = (blockIdx.x * blockDim.x + threadIdx.x) >> 6;
    int lane = threadIdx.x & 63;
    if (gw >= N) return;
    int sub = lane >> 3;    // which edge within the 8-group
    int q   = lane & 7;     // which 16B quarter... (eighth) of the row

    int beg = rowptr[gw], end = rowptr[gw + 1];
    int deg = end - beg;

    const char* gb = (const char*)gin;

    // hoisted epilogue operands (overlap with gather latency)
    float di    = dinv[gw];
    float4 giv  = *(const float4*)(gb + (size_t)gw * 128 + q * 16);                 // self-loop
    float4 g0v4 = *(const float4*)((const char*)g0f + (size_t)gw * 128 + q * 16);   // teleport

    float a[8] = {};   // 8 f32 accumulators = this lane's 8 output columns

    for (int base = 0; base < deg; base += 32) {
        int m = deg - base; if (m > 32) m = 32;
        int l32 = lane & 31;
        int ci = cols[beg + base + (l32 < m ? l32 : 0)];   // 32 cols, one load
#pragma unroll
        for (int i = 0; i < 4; ++i) {
            int e = i * 8 + sub;                 // edge index within this 32-group
            int c = __shfl(ci, e, 64);           // distribute col to the 8-lane group
            if (base + e >= deg) c = N;          // dummy zero row (L1-resident)
            float4 v = *(const float4*)(gb + (size_t)c * 128 + q * 16);
            const __half2* h2 = (const __half2*)&v;
#pragma unroll
            for (int u = 0; u < 4; ++u) {
                float2 f = __half22float2(h2[u]);
                a[2 * u]     += f.x;
                a[2 * u + 1] += f.y;
            }
        }
    }

    // reduce across the 8 edge slots (lanes with equal q)
#pragma unroll
    for (int off = 8; off < 64; off <<= 1) {
#pragma unroll
        for (int u = 0; u < 8; ++u) a[u] += __shfl_xor(a[u], off, 64);
    }

    if (sub == 0) {   // 8 lanes, each owns cols [8q, 8q+8)
        const __half2* gih = (const __half2*)&giv;
        const __half2* g0h2 = (const __half2*)&g0v4;
        float r[8];
#pragma unroll
        for (int u = 0; u < 4; ++u) {
            float2 gi = __half22float2(gih[u]);
            float2 g0 = __half22float2(g0h2[u]);
            r[2 * u]     = 0.9f * di * (a[2 * u]     + gi.x) + 0.1f * g0.x;
            r[2 * u + 1] = 0.9f * di * (a[2 * u + 1] + gi.y) + 0.1f * g0.y;
        }
        if (final_step) {
            float4 b0 = ((const float4*)bias)[2 * q];
            float4 b1 = ((const float4*)bias)[2 * q + 1];
            float4 o0 = make_float4(r[0] + b0.x, r[1] + b0.y, r[2] + b0.z, r[3] + b0.w);
            float4 o1 = make_float4(r[4] + b1.x, r[5] + b1.y, r[6] + b1.z, r[7] + b1.w);
            float4* op = (float4*)(outf + (size_t)gw * 64 + q * 8);
            op[0] = o0; op[1] = o1;
        } else {
            __half2 o[4];
#pragma unroll
            for (int u = 0; u < 4; ++u)
                o[u] = __floats2half2_rn(di * r[2 * u], di * r[2 * u + 1]);
            *(float4*)((char*)gout + (size_t)gw * 128 + q * 16) = *(float4*)o;
        }
    }
}

// ---------------- launch ----------------

extern "C" void kernel_launch(void* const* d_in, const int* in_sizes, int n_in,
                              void* d_out, int out_size, void* d_ws, size_t ws_size,
                              hipStream_t stream) {
    const float* x  = (const float*)d_in[0];
    const int*   ei = (const int*)d_in[1];
    const float* W  = (const float*)d_in[2];
    const float* b  = (const float*)d_in[3];
    float* out = (float*)d_out;

    const int N = in_sizes[0] / 128;
    const int E = in_sizes[1] / 2;
    const int* src = ei;
    const int* dst = ei + E;
    const int NB = (N + 255) >> BSH;     // buckets of 256 dsts

    char* w = (char*)d_ws;
    size_t off = 0;
    auto alloc = [&](size_t bytes) -> void* {
        void* p = w + off;
        off += (bytes + 255) & ~(size_t)255;
        return p;
    };
    const size_t fp16buf = (size_t)(N + 1) * 32 * sizeof(__half2);  // 128 B/row
    __half2*  g0h    = (__half2*) alloc(fp16buf);   // +1 dummy row
    __half2*  bufA   = (__half2*) alloc(fp16buf);
    __half2*  bufB   = (__half2*) alloc(fp16buf);
    __half2*  g0f    = (__half2*) alloc(fp16buf);
    int*      cols   = (int*)     alloc((size_t)E * 4);
    unsigned* binned = (unsigned*)alloc((size_t)E * 4);
    int*      rowptr = (int*)     alloc((size_t)(N + 1) * 4);
    int*      bktcnt = (int*)     alloc((size_t)NB * 4);
    int*      bktbase= (int*)     alloc((size_t)(NB + 1) * 4);
    int*      bktcur = (int*)     alloc((size_t)NB * 16 * 4);    // 64B-padded
    float*    dinvv  = (float*)   alloc((size_t)N * 4);

    const int nblkB = (E + 4095) / 4096;

    // ---- build dst-CSR: bucket hist -> scan -> binsort -> per-bucket fill ----
    zero_i32<<<(NB + 255) / 256, 256, 0, stream>>>(bktcnt, NB);
    bucket_hist_k<<<nblkB, 256, 0, stream>>>(dst, E, bktcnt);
    zero_dummy<<<1, 96, 0, stream>>>(g0h, bufA, bufB, N);
    bucket_scan_k<<<1, 256, 0, stream>>>(bktcnt, NB, E, bktbase, bktcur);
    binsort_k<<<nblkB, 256, 0, stream>>>(src, dst, E, bktcur, binned);
    fill2_k<<<NB, 256, 0, stream>>>(binned, bktbase, N, E, NB, rowptr, dinvv, cols);

    // g0 = x @ W (propagation commutes with the linear head)
    gemm_k<<<(N + 63) / 64, 256, 0, stream>>>(x, W, dinvv, g0f, g0h, N);

    // K = 10 APPNP steps, fp16 ping-pong; last step writes fp32 d_out (+bias)
    const int nblkP = (N * 64 + 255) / 256;
    const __half2* gin = g0h;
    __half2* pp[2] = {bufA, bufB};
    for (int k = 0; k < 10; ++k) {
        const bool fin = (k == 9);
        __half2* gout = pp[k & 1];
        prop_k<<<nblkP, 256, 0, stream>>>(gin, g0f, gout, out, rowptr, cols,
                                          dinvv, b, N, fin ? 1 : 0);
        gin = gout;
    }
}

// Round 2
// 753.421 us; speedup vs baseline: 1.1584x; 1.0088x over previous
//
#include <hip/hip_runtime.h>
#include <hip/hip_fp16.h>
#include <math.h>

// dst-CSR built with ZERO N-wide passes (unchanged):
//   bucket_hist_k / bucket_scan_k / binsort_k / fill2_k.
// gemm_k: no W staging (L1-resident), 64-row x tile -> 4 blocks/CU.
// prop_k (this round): unmasked 32-edge main groups + 8-edge tail
//   (-26% gathers vs masked-32), and v_dot2_f32_f16 accumulation
//   (1 instr per fp16 lane, exact f32 accumulate) replacing cvt+add.

#define BSH 8   // 256 dsts per bucket

typedef _Float16 h2_t __attribute__((ext_vector_type(2)));

// ---------------- small utils ----------------

__global__ void zero_i32(int* __restrict__ p, int n) {
    int i = blockIdx.x * blockDim.x + threadIdx.x;
    if (i < n) p[i] = 0;
}

// zero dummy row N (32 half2) of the three gather buffers
__global__ void zero_dummy(__half2* __restrict__ b0, __half2* __restrict__ b1,
                           __half2* __restrict__ b2, int N) {
    int t = threadIdx.x;
    if (t >= 96) return;
    __half2* b = (t < 32) ? b0 : (t < 64) ? b1 : b2;
    b[(size_t)N * 32 + (t & 31)] = __floats2half2_rn(0.f, 0.f);
}

// ---------------- bucket histogram (LDS-aggregated) ----------------

__global__ void __launch_bounds__(256) bucket_hist_k(const int* __restrict__ dst, int E,
                                                     int* __restrict__ bktcnt) {
    __shared__ int hist[400];
    int t = threadIdx.x;
    for (int i = t; i < 400; i += 256) hist[i] = 0;
    __syncthreads();
    int e0 = blockIdx.x * 4096 + t;
#pragma unroll
    for (int i = 0; i < 16; ++i) {
        int e = e0 + i * 256;
        if (e < E) atomicAdd(&hist[dst[e] >> BSH], 1);
    }
    __syncthreads();
    for (int b = t; b < 400; b += 256) {
        int c = hist[b];
        if (c > 0) atomicAdd(&bktcnt[b], c);
    }
}

// ---------------- 1-block scan of bucket totals -> bases + padded cursors ----------------

__global__ void bucket_scan_k(const int* __restrict__ bktcnt, int nb, int E,
                              int* __restrict__ bktbase, int* __restrict__ bktcur) {
    __shared__ int s[256];
    int t = threadIdx.x;
    int C = (nb + 255) / 256;            // <= 8
    int b0 = t * C;
    int loc[8]; int sum = 0;
    for (int i = 0; i < C; ++i) {
        int v = (b0 + i < nb) ? bktcnt[b0 + i] : 0;
        loc[i] = sum; sum += v;
    }
    s[t] = sum; __syncthreads();
    for (int off = 1; off < 256; off <<= 1) {
        int v = (t >= off) ? s[t - off] : 0;
        __syncthreads();
        s[t] += v;
        __syncthreads();
    }
    int excl = s[t] - sum;
    for (int i = 0; i < C; ++i)
        if (b0 + i < nb) {
            int e0 = excl + loc[i];
            bktbase[b0 + i] = e0;
            bktcur[(b0 + i) * 16] = e0;  // 64B-padded cursor
        }
    if (t == 0) bktbase[nb] = E;
}

// ---------------- bin edges by bucket (dst>>8), contiguous runs ----------------

__global__ void __launch_bounds__(256) binsort_k(const int* __restrict__ src,
                                                 const int* __restrict__ dst, int E,
                                                 int* __restrict__ bktcur,  // padded x16
                                                 unsigned* __restrict__ binned) {
    __shared__ int hist[400], gbase[400], lcur[400];
    int t = threadIdx.x;
    for (int i = t; i < 400; i += 256) { hist[i] = 0; lcur[i] = 0; }
    __syncthreads();

    int e0 = blockIdx.x * 4096 + t;
    unsigned rec[16]; int bk[16];
#pragma unroll
    for (int i = 0; i < 16; ++i) {
        int e = e0 + i * 256;
        if (e < E) {
            int s = src[e], d = dst[e];
            bk[i]  = d >> BSH;
            rec[i] = ((unsigned)s << BSH) | (unsigned)(d & 255);
            atomicAdd(&hist[bk[i]], 1);
        } else bk[i] = -1;
    }
    __syncthreads();
    for (int b = t; b < 400; b += 256) {
        int c = hist[b];
        if (c > 0) gbase[b] = atomicAdd(&bktcur[b * 16], c);
    }
    __syncthreads();
#pragma unroll
    for (int i = 0; i < 16; ++i) {
        if (bk[i] >= 0) {
            int loc = atomicAdd(&lcur[bk[i]], 1);
            binned[gbase[bk[i]] + loc] = rec[i];
        }
    }
}

// ---------------- per-bucket: degrees + rowptr + dinv + col scatter ----------------

__global__ void __launch_bounds__(256) fill2_k(const unsigned* __restrict__ binned,
                                               const int* __restrict__ bktbase,
                                               int N, int E, int NB,
                                               int* __restrict__ rowptr,
                                               float* __restrict__ dinv,
                                               int* __restrict__ col) {
    __shared__ int cnt[256], excl[256], lcur[256];
    int b = blockIdx.x, t = threadIdx.x;
    int beg = bktbase[b], end = bktbase[b + 1];
    cnt[t] = 0;
    __syncthreads();
    for (int i = beg + t; i < end; i += 256)
        atomicAdd(&cnt[binned[i] & 255u], 1);
    __syncthreads();
    int v = cnt[t];
    excl[t] = v;
    __syncthreads();
    for (int off = 1; off < 256; off <<= 1) {
        int u = (t >= off) ? excl[t - off] : 0;
        __syncthreads();
        excl[t] += u;
        __syncthreads();
    }
    int ex = excl[t] - v;                // exclusive prefix within bucket
    lcur[t] = ex;
    int d = (b << BSH) + t;
    if (d < N) {
        rowptr[d] = beg + ex;            // coalesced
        dinv[d] = rsqrtf((float)(v + 1));  // +1 self-loop
    }
    if (b == NB - 1 && t == 0) rowptr[N] = E;
    __syncthreads();
    for (int i = beg + t; i < end; i += 256) {
        unsigned r = binned[i];
        int loc = atomicAdd(&lcur[r & 255u], 1);
        col[beg + loc] = (int)(r >> BSH);   // scatter inside this bucket's segment
    }
}

// ---------------- g0 = x @ W : 64-row tile, W read from global (L1-resident) ----------------

__global__ void __launch_bounds__(256) gemm_k(const float* __restrict__ x,
                                              const float* __restrict__ W,
                                              const float* __restrict__ dinv,
                                              __half2* __restrict__ g0f,
                                              __half2* __restrict__ g0h, int N) {
    __shared__ float xs[64 * 133];        // ~34 KB -> 4 blocks/CU
    int t = threadIdx.x;
    int n0 = blockIdx.x * 64;
    for (int f = t; f < 64 * 32; f += 256) {
        int r = f >> 5, c4 = f & 31;
        int n = n0 + r;
        float4 v = (n < N) ? ((const float4*)x)[(size_t)n * 32 + c4]
                           : make_float4(0.f, 0.f, 0.f, 0.f);
        float* dp = &xs[r * 133 + c4 * 4];
        dp[0] = v.x; dp[1] = v.y; dp[2] = v.z; dp[3] = v.w;
    }
    __syncthreads();
    int tr = t & 15, tc = t >> 4;
    int j0 = tr * 4, r0 = tc * 4;
    const float4* W4 = (const float4*)W;  // 32 KB total -> L1-resident
    float acc[4][4] = {};
#pragma unroll 8
    for (int k = 0; k < 128; ++k) {
        float4 wv = W4[k * 16 + tr];      // 256 B/k, broadcast across tc, L1 hit
#pragma unroll
        for (int i = 0; i < 4; ++i) {
            float xv = xs[(r0 + i) * 133 + k];
            acc[i][0] += xv * wv.x; acc[i][1] += xv * wv.y;
            acc[i][2] += xv * wv.z; acc[i][3] += xv * wv.w;
        }
    }
    int h0 = j0 >> 1;
#pragma unroll
    for (int i = 0; i < 4; ++i) {
        int n = n0 + r0 + i;
        if (n < N) {
            float dn = dinv[n];
            __half2* gf = &g0f[(size_t)n * 32 + h0];
            gf[0] = __floats2half2_rn(acc[i][0], acc[i][1]);
            gf[1] = __floats2half2_rn(acc[i][2], acc[i][3]);
            __half2* gp = &g0h[(size_t)n * 32 + h0];
            gp[0] = __floats2half2_rn(acc[i][0] * dn, acc[i][1] * dn);
            gp[1] = __floats2half2_rn(acc[i][2] * dn, acc[i][3] * dn);
        }
    }
}

// ---------------- propagation: 8 lanes per row, float4 gathers ----------------
// Wave = 1 dst row. lane = sub*8 + q: sub in [0,8) = edge slot, q in [0,8) =
// 16B segment of the 128 B fp16 row. Main loop: full 32-edge groups, no
// masking. Tail: 8-edge steps, masked to dummy row N. Accumulation via
// v_dot2_f32_f16 (b = (1,0)/(0,1)): one instr per fp16 lane, exact f32.

__global__ void __launch_bounds__(256) prop_k(const __half2* __restrict__ gin,
                                              const __half2* __restrict__ g0f,
                                              __half2* __restrict__ gout,
                                              float* __restrict__ outf,
                                              const int* __restrict__ rowptr,
                                              const int* __restrict__ cols,
                                              const float* __restrict__ dinv,
                                              const float* __restrict__ bias,
                                              int N, int final_step) {
    int gw = (blockIdx.x * blockDim.x + threadIdx.x) >> 6;
    int lane = threadIdx.x & 63;
    if (gw >= N) return;
    int sub = lane >> 3;    // edge slot within the 8-group
    int q   = lane & 7;     // 16B segment of the row
    int l32 = lane & 31;

    int beg = rowptr[gw], end = rowptr[gw + 1];
    int deg = end - beg;

    const char* gb = (const char*)gin;

    // hoisted epilogue operands (overlap with gather latency)
    float di    = dinv[gw];
    float4 giv  = *(const float4*)(gb + (size_t)gw * 128 + q * 16);                 // self-loop
    float4 g0v4 = *(const float4*)((const char*)g0f + (size_t)gw * 128 + q * 16);   // teleport

    const h2_t SEL_LO = {(_Float16)1.f, (_Float16)0.f};
    const h2_t SEL_HI = {(_Float16)0.f, (_Float16)1.f};

    float a[8] = {};   // 8 f32 accumulators = this lane's 8 output columns

    int full = deg & ~31;
    for (int base = 0; base < full; base += 32) {
        int ci = cols[beg + base + l32];   // 32 cols, one load, all valid
#pragma unroll
        for (int i = 0; i < 4; ++i) {
            int c = __shfl(ci, i * 8 + sub, 64);
            float4 v = *(const float4*)(gb + (size_t)c * 128 + q * 16);
            union { float4 f; h2_t h[4]; } uv; uv.f = v;
#pragma unroll
            for (int u = 0; u < 4; ++u) {
                a[2 * u]     = __builtin_amdgcn_fdot2(uv.h[u], SEL_LO, a[2 * u],     false);
                a[2 * u + 1] = __builtin_amdgcn_fdot2(uv.h[u], SEL_HI, a[2 * u + 1], false);
            }
        }
    }
    int m = deg - full;                    // 0..31 tail edges
    if (m > 0) {
        int ci = cols[beg + full + (l32 < m ? l32 : 0)];
#pragma unroll 4
        for (int i = 0; i * 8 < m; ++i) {
            int e = i * 8 + sub;
            int c = __shfl(ci, e, 64);
            if (e >= m) c = N;             // dummy zero row (L1-resident)
            float4 v = *(const float4*)(gb + (size_t)c * 128 + q * 16);
            union { float4 f; h2_t h[4]; } uv; uv.f = v;
#pragma unroll
            for (int u = 0; u < 4; ++u) {
                a[2 * u]     = __builtin_amdgcn_fdot2(uv.h[u], SEL_LO, a[2 * u],     false);
                a[2 * u + 1] = __builtin_amdgcn_fdot2(uv.h[u], SEL_HI, a[2 * u + 1], false);
            }
        }
    }

    // reduce across the 8 edge slots (lanes with equal q)
#pragma unroll
    for (int off = 8; off < 64; off <<= 1) {
#pragma unroll
        for (int u = 0; u < 8; ++u) a[u] += __shfl_xor(a[u], off, 64);
    }

    if (sub == 0) {   // 8 lanes, each owns cols [8q, 8q+8)
        const __half2* gih  = (const __half2*)&giv;
        const __half2* g0h2 = (const __half2*)&g0v4;
        float r[8];
#pragma unroll
        for (int u = 0; u < 4; ++u) {
            float2 gi = __half22float2(gih[u]);
            float2 g0 = __half22float2(g0h2[u]);
            r[2 * u]     = 0.9f * di * (a[2 * u]     + gi.x) + 0.1f * g0.x;
            r[2 * u + 1] = 0.9f * di * (a[2 * u + 1] + gi.y) + 0.1f * g0.y;
        }
        if (final_step) {
            float4 b0 = ((const float4*)bias)[2 * q];
            float4 b1 = ((const float4*)bias)[2 * q + 1];
            float4 o0 = make_float4(r[0] + b0.x, r[1] + b0.y, r[2] + b0.z, r[3] + b0.w);
            float4 o1 = make_float4(r[4] + b1.x, r[5] + b1.y, r[6] + b1.z, r[7] + b1.w);
            float4* op = (float4*)(outf + (size_t)gw * 64 + q * 8);
            op[0] = o0; op[1] = o1;
        } else {
            __half2 o[4];
#pragma unroll
            for (int u = 0; u < 4; ++u)
                o[u] = __floats2half2_rn(di * r[2 * u], di * r[2 * u + 1]);
            *(float4*)((char*)gout + (size_t)gw * 128 + q * 16) = *(float4*)o;
        }
    }
}

// ---------------- launch ----------------

extern "C" void kernel_launch(void* const* d_in, const int* in_sizes, int n_in,
                              void* d_out, int out_size, void* d_ws, size_t ws_size,
                              hipStream_t stream) {
    const float* x  = (const float*)d_in[0];
    const int*   ei = (const int*)d_in[1];
    const float* W  = (const float*)d_in[2];
    const float* b  = (const float*)d_in[3];
    float* out = (float*)d_out;

    const int N = in_sizes[0] / 128;
    const int E = in_sizes[1] / 2;
    const int* src = ei;
    const int* dst = ei + E;
    const int NB = (N + 255) >> BSH;     // buckets of 256 dsts

    char* w = (char*)d_ws;
    size_t off = 0;
    auto alloc = [&](size_t bytes) -> void* {
        void* p = w + off;
        off += (bytes + 255) & ~(size_t)255;
        return p;
    };
    const size_t fp16buf = (size_t)(N + 1) * 32 * sizeof(__half2);  // 128 B/row
    __half2*  g0h    = (__half2*) alloc(fp16buf);   // +1 dummy row
    __half2*  bufA   = (__half2*) alloc(fp16buf);
    __half2*  bufB   = (__half2*) alloc(fp16buf);
    __half2*  g0f    = (__half2*) alloc(fp16buf);
    int*      cols   = (int*)     alloc((size_t)E * 4);
    unsigned* binned = (unsigned*)alloc((size_t)E * 4);
    int*      rowptr = (int*)     alloc((size_t)(N + 1) * 4);
    int*      bktcnt = (int*)     alloc((size_t)NB * 4);
    int*      bktbase= (int*)     alloc((size_t)(NB + 1) * 4);
    int*      bktcur = (int*)     alloc((size_t)NB * 16 * 4);    // 64B-padded
    float*    dinvv  = (float*)   alloc((size_t)N * 4);

    const int nblkB = (E + 4095) / 4096;

    // ---- build dst-CSR: bucket hist -> scan -> binsort -> per-bucket fill ----
    zero_i32<<<(NB + 255) / 256, 256, 0, stream>>>(bktcnt, NB);
    bucket_hist_k<<<nblkB, 256, 0, stream>>>(dst, E, bktcnt);
    zero_dummy<<<1, 96, 0, stream>>>(g0h, bufA, bufB, N);
    bucket_scan_k<<<1, 256, 0, stream>>>(bktcnt, NB, E, bktbase, bktcur);
    binsort_k<<<nblkB, 256, 0, stream>>>(src, dst, E, bktcur, binned);
    fill2_k<<<NB, 256, 0, stream>>>(binned, bktbase, N, E, NB, rowptr, dinvv, cols);

    // g0 = x @ W (propagation commutes with the linear head)
    gemm_k<<<(N + 63) / 64, 256, 0, stream>>>(x, W, dinvv, g0f, g0h, N);

    // K = 10 APPNP steps, fp16 ping-pong; last step writes fp32 d_out (+bias)
    const int nblkP = (N * 64 + 255) / 256;
    const __half2* gin = g0h;
    __half2* pp[2] = {bufA, bufB};
    for (int k = 0; k < 10; ++k) {
        const bool fin = (k == 9);
        __half2* gout = pp[k & 1];
        prop_k<<<nblkP, 256, 0, stream>>>(gin, g0f, gout, out, rowptr, cols,
                                          dinvv, b, N, fin ? 1 : 0);
        gin = gout;
    }
}